// Round 1
// baseline (458.068 us; speedup 1.0000x reference)
//
#include <hip/hip_runtime.h>
#include <math.h>

#define EPSF 1e-8f
#define HW 36864
#define NROW 192
#define NSY 49
#define OH 97
#define NPOS (8*9409)
#define NB_LOSS 512

// ws float offsets
#define OFF_INV 0
#define OFF_NORM 48
#define OFF_MEAN 96
#define OFF_MAX 144
#define OFF_PSUM 160
#define OFF_S 1024   // 48 * 9409 floats

#define USTRIDE 204  // 204%32=12 -> yp spreads banks; %4==0 for float4 align
#define VSTRIDE 324  // 324%32=4  -> yp spreads banks; %4==0
#define RSTRIDE 132

// ---------------- Kernel A: per-image mean / 1/(std+eps) / norm ----------------
__global__ __launch_bounds__(256) void stats_kernel(const float* __restrict__ pred,
                                                    const float* __restrict__ target,
                                                    float* __restrict__ ws) {
  int img = blockIdx.x;                 // img = t*24 + (b*3+c)
  int t = img / 24, local = img % 24;
  const float* src = (t ? target : pred) + (size_t)local * HW;
  int tid = threadIdx.x;
  float s = 0.f, sq = 0.f;
  const float4* src4 = (const float4*)src;
  for (int i = tid; i < HW/4; i += 256) {
    float4 v = src4[i];
    s  += (v.x + v.y) + (v.z + v.w);
    sq += (v.x*v.x + v.y*v.y) + (v.z*v.z + v.w*v.w);
  }
#pragma unroll
  for (int o = 32; o > 0; o >>= 1) { s += __shfl_down(s, o); sq += __shfl_down(sq, o); }
  __shared__ float rs[4], rq[4];
  int lane = tid & 63, wv = tid >> 6;
  if (lane == 0) { rs[wv] = s; rq[wv] = sq; }
  __syncthreads();
  if (tid == 0) {
    float S = (rs[0] + rs[1]) + (rs[2] + rs[3]);
    float Q = (rq[0] + rq[1]) + (rq[2] + rq[3]);
    float mean = S / (float)HW;
    float M2 = Q - S * S / (float)HW;
    M2 = fmaxf(M2, 0.f);
    float sd  = sqrtf(M2 / (float)(HW - 1));
    float inv = 1.f / (sd + EPSF);          // xn = (x-mean)*inv
    ws[OFF_MEAN + img] = mean;
    ws[OFF_INV  + img] = inv;
    ws[OFF_NORM + img] = sqrtf(M2) * inv;   // sqrt(sum xn^2)
    if (img == 0) { ws[OFF_MAX] = 0.f; ws[OFF_MAX + 1] = 0.f; }
  }
}

// ---------------- Kernel B: autocorrelation (heavy) ----------------
// One block per (img, sy in [0,48]). Computes C(sy,sx) for sx in [-48,48],
// writes S[48+sy][48+sx] and the symmetric S[48-sy][48-sx].
__global__ __launch_bounds__(128) void autocorr_kernel(const float* __restrict__ pred,
                                                       const float* __restrict__ target,
                                                       float* __restrict__ ws) {
  int bx = blockIdx.x;
  int img = bx / NSY;
  int sy  = bx - img * NSY;
  int t = img / 24, local = img % 24;
  const float* src = (t ? target : pred) + (size_t)local * HW;
  float mean  = ws[OFF_MEAN + img];
  float inv   = ws[OFF_INV  + img];
  float scale = inv * inv;                 // centered-autocorr -> xn-autocorr

  __shared__ float u[16 * USTRIDE];        // 16 kernel rows, centered
  __shared__ float vpad[16 * VSTRIDE];     // 16 shifted rows, 48-left-pad + zeros
  __shared__ float red[16 * RSTRIDE];

  int tid = threadIdx.x;
  int g  = tid & 7;        // shift group: s0 = 16g (shifts s0..s0+15, valid s<97)
  int yp = tid >> 3;       // row slot 0..15
  int s0 = g << 4;

  for (int i = tid; i < 16 * VSTRIDE; i += 128) vpad[i] = 0.f;  // pads stay zero

  float acc[16];
#pragma unroll
  for (int j = 0; j < 16; j++) acc[j] = 0.f;

  int R = 192 - sy;        // number of valid row pairs
  for (int ybase = 0; ybase < R; ybase += 16) {
    __syncthreads();       // previous compute done before restaging
    // stage 16 rows of u and vpad-center (48 float4 per row each)
    for (int i = tid; i < 16 * 48; i += 128) {
      int row = i / 48, c4 = i - row * 48;
      int y = ybase + row;
      bool valid = (y < R);
      int ys = valid ? y : 0;
      int yv = valid ? (y + sy) : 0;
      float4 a = ((const float4*)(src + (size_t)ys * 192))[c4];
      float4 b = ((const float4*)(src + (size_t)yv * 192))[c4];
      float4 um, vm;
      if (valid) {
        um.x = a.x - mean; um.y = a.y - mean; um.z = a.z - mean; um.w = a.w - mean;
        vm.x = b.x - mean; vm.y = b.y - mean; vm.z = b.z - mean; vm.w = b.w - mean;
      } else {
        um.x = um.y = um.z = um.w = 0.f;
        vm.x = vm.y = vm.z = vm.w = 0.f;
      }
      *((float4*)&u[row * USTRIDE + c4 * 4]) = um;
      *((float4*)&vpad[row * VSTRIDE + 48 + c4 * 4]) = vm;
    }
    __syncthreads();

    const float4* vrow4 = (const float4*)&vpad[yp * VSTRIDE];
    const float4* urow4 = (const float4*)&u[yp * USTRIDE];
    int sb = s0 >> 2;
    float w[20];
    {
      float4 a = vrow4[sb + 0]; w[0] = a.x; w[1] = a.y; w[2]  = a.z; w[3]  = a.w;
      float4 b = vrow4[sb + 1]; w[4] = b.x; w[5] = b.y; w[6]  = b.z; w[7]  = b.w;
      float4 c = vrow4[sb + 2]; w[8] = c.x; w[9] = c.y; w[10] = c.z; w[11] = c.w;
      float4 d = vrow4[sb + 3]; w[12]= d.x; w[13]= d.y; w[14] = d.z; w[15] = d.w;
    }
#pragma unroll 4
    for (int xb = 0; xb < 48; ++xb) {
      float4 nv = vrow4[sb + xb + 4];
      w[16] = nv.x; w[17] = nv.y; w[18] = nv.z; w[19] = nv.w;
      float4 uu = urow4[xb];
#pragma unroll
      for (int j = 0; j < 16; j++) {
        acc[j] += uu.x * w[j];
        acc[j] += uu.y * w[j + 1];
        acc[j] += uu.z * w[j + 2];
        acc[j] += uu.w * w[j + 3];
      }
#pragma unroll
      for (int k = 0; k < 16; k++) w[k] = w[k + 4];   // slide window by 4
    }
  }

  __syncthreads();
#pragma unroll
  for (int j = 0; j < 16; j++) red[yp * RSTRIDE + s0 + j] = acc[j];
  __syncthreads();

  if (tid < OH) {                 // s = tid -> sx = s-48
    float v = 0.f;
#pragma unroll
    for (int yy = 0; yy < 16; ++yy) v += red[yy * RSTRIDE + tid];
    v *= scale;
    float* S = ws + OFF_S + (size_t)img * 9409;
    S[(48 + sy) * OH + tid] = v;
    if (sy > 0) S[(48 - sy) * OH + (96 - tid)] = v;   // C(-sy,-sx)=C(sy,sx)
  }
}

// ---------------- Kernel C: global max of P (pred) and T (target) ----------------
__global__ __launch_bounds__(256) void max_kernel(float* __restrict__ ws) {
  __shared__ float wsh[48];      // (1/3)/(norm+eps), [t*24 + i*3 + c]
  int tid = threadIdx.x;
  if (tid < 48) wsh[tid] = (1.f / 3.f) / (ws[OFF_NORM + tid] + EPSF);
  __syncthreads();
  float mp = 0.f, mt = 0.f;      // true max is the positive zero-shift peak
  const float* S = ws + OFF_S;
  for (int idx = blockIdx.x * 256 + tid; idx < NPOS; idx += gridDim.x * 256) {
    int b = idx / 9409, r = idx - b * 9409;
    size_t pb = (size_t)(b * 3) * 9409 + r;
    size_t tb = (size_t)(24 + b * 3) * 9409 + r;
    float p0 = S[pb], p1 = S[pb + 9409], p2 = S[pb + 2 * 9409];
    float q0 = S[tb], q1 = S[tb + 9409], q2 = S[tb + 2 * 9409];
#pragma unroll
    for (int i = 0; i < 8; i++) {
      float pv = p0 * wsh[i*3] + p1 * wsh[i*3+1] + p2 * wsh[i*3+2];
      float tv = q0 * wsh[24+i*3] + q1 * wsh[24+i*3+1] + q2 * wsh[24+i*3+2];
      mp = fmaxf(mp, pv); mt = fmaxf(mt, tv);
    }
  }
#pragma unroll
  for (int o = 32; o > 0; o >>= 1) { mp = fmaxf(mp, __shfl_down(mp, o)); mt = fmaxf(mt, __shfl_down(mt, o)); }
  __shared__ float rp[4], rt[4];
  int lane = tid & 63, wv = tid >> 6;
  if (!lane) { rp[wv] = mp; rt[wv] = mt; }
  __syncthreads();
  if (!tid) {
    mp = fmaxf(fmaxf(rp[0], rp[1]), fmaxf(rp[2], rp[3]));
    mt = fmaxf(fmaxf(rt[0], rt[1]), fmaxf(rt[2], rt[3]));
    atomicMax((int*)ws + OFF_MAX,     __float_as_int(mp));   // positive floats: int order == float order
    atomicMax((int*)ws + OFF_MAX + 1, __float_as_int(mt));
  }
}

// ---------------- Kernel D: per-block partial |P/mp - T/mt| sums ----------------
__global__ __launch_bounds__(256) void loss_kernel(float* __restrict__ ws) {
  __shared__ float wsh[48];
  int tid = threadIdx.x;
  if (tid < 48) wsh[tid] = (1.f / 3.f) / (ws[OFF_NORM + tid] + EPSF);
  __syncthreads();
  float imp = 1.f / (ws[OFF_MAX] + EPSF);
  float imt = 1.f / (ws[OFF_MAX + 1] + EPSF);
  float acc = 0.f;
  const float* S = ws + OFF_S;
  for (int idx = blockIdx.x * 256 + tid; idx < NPOS; idx += NB_LOSS * 256) {
    int b = idx / 9409, r = idx - b * 9409;
    size_t pb = (size_t)(b * 3) * 9409 + r;
    size_t tb = (size_t)(24 + b * 3) * 9409 + r;
    float p0 = S[pb], p1 = S[pb + 9409], p2 = S[pb + 2 * 9409];
    float q0 = S[tb], q1 = S[tb + 9409], q2 = S[tb + 2 * 9409];
#pragma unroll
    for (int i = 0; i < 8; i++) {
      float pv = (p0 * wsh[i*3] + p1 * wsh[i*3+1] + p2 * wsh[i*3+2]) * imp;
      float tv = (q0 * wsh[24+i*3] + q1 * wsh[24+i*3+1] + q2 * wsh[24+i*3+2]) * imt;
      acc += fabsf(pv - tv);
    }
  }
#pragma unroll
  for (int o = 32; o > 0; o >>= 1) acc += __shfl_down(acc, o);
  __shared__ float r[4];
  int lane = tid & 63, wv = tid >> 6;
  if (!lane) r[wv] = acc;
  __syncthreads();
  if (!tid) ws[OFF_PSUM + blockIdx.x] = (r[0] + r[1]) + (r[2] + r[3]);
}

// ---------------- Kernel E: final fixed-order reduce ----------------
__global__ __launch_bounds__(256) void final_kernel(const float* __restrict__ ws,
                                                    float* __restrict__ out) {
  int tid = threadIdx.x;
  float s = ws[OFF_PSUM + tid] + ws[OFF_PSUM + 256 + tid];
#pragma unroll
  for (int o = 32; o > 0; o >>= 1) s += __shfl_down(s, o);
  __shared__ float r[4];
  int lane = tid & 63, wv = tid >> 6;
  if (!lane) r[wv] = s;
  __syncthreads();
  if (!tid) out[0] = ((r[0] + r[1]) + (r[2] + r[3])) / 602176.0f;  // mean over 8*8*97*97
}

extern "C" void kernel_launch(void* const* d_in, const int* in_sizes, int n_in,
                              void* d_out, int out_size, void* d_ws, size_t ws_size,
                              hipStream_t stream) {
  const float* pred   = (const float*)d_in[0];
  const float* target = (const float*)d_in[1];
  float* ws  = (float*)d_ws;
  float* out = (float*)d_out;

  hipLaunchKernelGGL(stats_kernel,    dim3(48),        dim3(256), 0, stream, pred, target, ws);
  hipLaunchKernelGGL(autocorr_kernel, dim3(48 * NSY),  dim3(128), 0, stream, pred, target, ws);
  hipLaunchKernelGGL(max_kernel,      dim3(256),       dim3(256), 0, stream, ws);
  hipLaunchKernelGGL(loss_kernel,     dim3(NB_LOSS),   dim3(256), 0, stream, ws);
  hipLaunchKernelGGL(final_kernel,    dim3(1),         dim3(256), 0, stream, ws, out);
}

// Round 2
// 98.641 us; speedup vs baseline: 4.6438x; 4.6438x over previous
//
#include <hip/hip_runtime.h>
#include <hip/hip_bf16.h>
#include <math.h>

#define EPSF 1e-8f
#define HW 36864
#define OH 97
#define NPOS (8*9409)
#define NB_LOSS 512

// ws float offsets
#define OFF_INV 0
#define OFF_NORM 48
#define OFF_MEAN 96
#define OFF_MAX 144
#define OFF_PSUM 160
#define OFF_S 1024   // 48 * 9409 floats

// MFMA autocorr geometry
#define CY 12        // rows per y-chunk; 16 chunks/image; 768 blocks
#define AROWS 75     // CY-1 + 63 + 1
#define APITCH 200   // bf16 elems (400B, 16B-aligned rows, bank-balanced)
#define BCPITCH 154  // dwords per parity copy (308 bf16 = 616B)

typedef short short8 __attribute__((ext_vector_type(8)));
typedef short short4v __attribute__((ext_vector_type(4)));
typedef float f32x4 __attribute__((ext_vector_type(4)));

__device__ __forceinline__ unsigned int pk2(float a, float b) {
  union { float f; unsigned int u; } x, y;
  x.f = a; y.f = b;
  unsigned int ra = x.u + 0x7fffu + ((x.u >> 16) & 1u);   // RNE to bf16
  unsigned int rb = y.u + 0x7fffu + ((y.u >> 16) & 1u);
  return (ra >> 16) | (rb & 0xffff0000u);
}

// ---------------- Kernel A: per-image mean / 1/(std+eps) / norm ----------------
__global__ __launch_bounds__(256) void stats_kernel(const float* __restrict__ pred,
                                                    const float* __restrict__ target,
                                                    float* __restrict__ ws) {
  int img = blockIdx.x;                 // img = t*24 + (b*3+c)
  int t = img / 24, local = img % 24;
  const float* src = (t ? target : pred) + (size_t)local * HW;
  int tid = threadIdx.x;
  float s = 0.f, sq = 0.f;
  const float4* src4 = (const float4*)src;
  for (int i = tid; i < HW/4; i += 256) {
    float4 v = src4[i];
    s  += (v.x + v.y) + (v.z + v.w);
    sq += (v.x*v.x + v.y*v.y) + (v.z*v.z + v.w*v.w);
  }
#pragma unroll
  for (int o = 32; o > 0; o >>= 1) { s += __shfl_down(s, o); sq += __shfl_down(sq, o); }
  __shared__ float rs[4], rq[4];
  int lane = tid & 63, wv = tid >> 6;
  if (lane == 0) { rs[wv] = s; rq[wv] = sq; }
  __syncthreads();
  if (tid == 0) {
    float S = (rs[0] + rs[1]) + (rs[2] + rs[3]);
    float Q = (rq[0] + rq[1]) + (rq[2] + rq[3]);
    float mean = S / (float)HW;
    float M2 = Q - S * S / (float)HW;
    M2 = fmaxf(M2, 0.f);
    float sd  = sqrtf(M2 / (float)(HW - 1));
    float inv = 1.f / (sd + EPSF);          // xn = (x-mean)*inv
    ws[OFF_MEAN + img] = mean;
    ws[OFF_INV  + img] = inv;
    ws[OFF_NORM + img] = sqrtf(M2) * inv;   // sqrt(sum xn^2)
    if (img == 0) { ws[OFF_MAX] = 0.f; ws[OFF_MAX + 1] = 0.f; }
  }
}

// ---------------- Kernel B: autocorrelation via bf16 MFMA ----------------
// Block = (img, 12-row y-chunk). Wave w owns sy-tile [16w,16w+16); 7 sx-tiles.
// D[sy][s] = sum_{y0,x} u[y0+sy][x] * u[y0][x - (s-48)], accumulated into S by atomicAdd.
__global__ __launch_bounds__(256) void autocorr_mfma(const float* __restrict__ pred,
                                                     const float* __restrict__ target,
                                                     float* __restrict__ ws) {
  int blk = blockIdx.x;
  int img = blk >> 4;
  int chunk = blk & 15;
  int Y = chunk * CY;
  int tsel = img / 24, local = img % 24;
  const float* src = (tsel ? target : pred) + (size_t)local * HW;
  float mean  = ws[OFF_MEAN + img];
  float inv   = ws[OFF_INV  + img];
  float scale = inv * inv;

  __shared__ __align__(16) unsigned short Albs[AROWS * APITCH];   // 30000 B
  __shared__ __align__(16) unsigned int   Blds[2 * 4 * BCPITCH];  // 4928 B (2 buf x 4 parity copies)

  int tid = threadIdx.x;
  int w = tid >> 6, lane = tid & 63, c = lane & 15, h = lane >> 4;

  // ---- stage A: rows Y..Y+74, centered bf16, zero beyond image ----
  for (int idx = tid; idx < AROWS * 48; idx += 256) {
    int r = idx / 48, c4 = idx - r * 48;
    int y = Y + r;
    float4 v;
    if (y < 192) v = ((const float4*)(src + (size_t)y * 192))[c4];
    else { v.x = v.y = v.z = v.w = 0.f; }
    unsigned int d0, d1;
    if (y < 192) { d0 = pk2(v.x - mean, v.y - mean); d1 = pk2(v.z - mean, v.w - mean); }
    else { d0 = 0u; d1 = 0u; }
    uint2 dd; dd.x = d0; dd.y = d1;
    *(uint2*)&Albs[r * APITCH + c4 * 4] = dd;
  }

  // ---- B staging: 4 parity-shifted copies of padded row y0 into buffer b ----
  auto stageB = [&](int y0, int b) {
    int t = tid;
    if (t < 152) {
      const float* row = src + (size_t)y0 * 192;
      int e0 = 2 * t - 64;
      float f[6];
#pragma unroll
      for (int q = 0; q < 6; q++) {
        int x = e0 + q;
        f[q] = (x >= 0 && x < 192) ? (row[x] - mean) : 0.f;
      }
      unsigned int d0 = pk2(f[0], f[1]), d1 = pk2(f[2], f[3]), d2 = pk2(f[4], f[5]);
      unsigned int* B32 = Blds + b * 4 * BCPITCH;
      B32[0 * BCPITCH + t] = d0;                           // copy se=0
      B32[1 * BCPITCH + t] = (d0 >> 16) | (d1 << 16);      // se=1
      B32[2 * BCPITCH + t] = d1;                           // se=2
      B32[3 * BCPITCH + t] = (d1 >> 16) | (d2 << 16);      // se=3
    }
  };

  // per-lane constant byte offset into a B buffer (parity copy select + lane slide)
  int se = (4 - (c & 3)) & 3;
  int LC = se * 614 + 16 * h - 2 * c + 32;   // = se*616 + (2*v0 + 128 - 2*se) - 32*i  with v0 at i=0

  f32x4 acc[7];
#pragma unroll
  for (int n = 0; n < 7; n++) { acc[n][0] = 0.f; acc[n][1] = 0.f; acc[n][2] = 0.f; acc[n][3] = 0.f; }

  const char* Abase = (const char*)Albs + (16 * w + c) * 400 + 16 * h;
  const char* Bbase = (const char*)Blds + LC;

  stageB(Y, 0);
  __syncthreads();

  for (int i = 0; i < CY; i++) {
    if (i) __syncthreads();
    if (i + 1 < CY) stageB(Y + i + 1, (i + 1) & 1);

    const char* pA = Abase + i * 400;
    const char* pB = Bbase + (i & 1) * (4 * BCPITCH * 4);

    short8 Wf[17];
    auto loadB = [&](int wi) {
      short4v lo = *(const short4v*)(pB + 32 * wi);
      short4v hi = *(const short4v*)(pB + 32 * wi + 8);
      short8 r;
      r[0] = lo[0]; r[1] = lo[1]; r[2] = lo[2]; r[3] = lo[3];
      r[4] = hi[0]; r[5] = hi[1]; r[6] = hi[2]; r[7] = hi[3];
      return r;
    };
#pragma unroll
    for (int k = 0; k < 7; k++) Wf[k] = loadB(k);
#pragma unroll
    for (int t = 0; t < 6; t++) {
      if (t) { Wf[2 * t + 5] = loadB(2 * t + 5); Wf[2 * t + 6] = loadB(2 * t + 6); }
      short8 Af = *(const short8*)(pA + 64 * t);
#pragma unroll
      for (int nt = 0; nt < 7; nt++)
        acc[nt] = __builtin_amdgcn_mfma_f32_16x16x32_bf16(Af, Wf[2 * t + 6 - nt], acc[nt], 0, 0, 0);
    }
  }

  // ---- epilogue: scale + atomic accumulate (and sy<->-sy symmetry) ----
  float* S = ws + OFF_S + (size_t)img * 9409;
#pragma unroll
  for (int nt = 0; nt < 7; nt++) {
    int s = 16 * nt + c;
    if (s <= 96) {
#pragma unroll
      for (int r = 0; r < 4; r++) {
        int sy = 16 * w + 4 * h + r;
        if (sy <= 48) {
          float v = acc[nt][r] * scale;
          atomicAdd(&S[(48 + sy) * OH + s], v);
          if (sy > 0) atomicAdd(&S[(48 - sy) * OH + (96 - s)], v);
        }
      }
    }
  }
}

// ---------------- Kernel C: global max of P (pred) and T (target) ----------------
__global__ __launch_bounds__(256) void max_kernel(float* __restrict__ ws) {
  __shared__ float wsh[48];      // (1/3)/(norm+eps), [t*24 + i*3 + c]
  int tid = threadIdx.x;
  if (tid < 48) wsh[tid] = (1.f / 3.f) / (ws[OFF_NORM + tid] + EPSF);
  __syncthreads();
  float mp = 0.f, mt = 0.f;
  const float* S = ws + OFF_S;
  for (int idx = blockIdx.x * 256 + tid; idx < NPOS; idx += gridDim.x * 256) {
    int b = idx / 9409, r = idx - b * 9409;
    size_t pb = (size_t)(b * 3) * 9409 + r;
    size_t tb = (size_t)(24 + b * 3) * 9409 + r;
    float p0 = S[pb], p1 = S[pb + 9409], p2 = S[pb + 2 * 9409];
    float q0 = S[tb], q1 = S[tb + 9409], q2 = S[tb + 2 * 9409];
#pragma unroll
    for (int i = 0; i < 8; i++) {
      float pv = p0 * wsh[i*3] + p1 * wsh[i*3+1] + p2 * wsh[i*3+2];
      float tv = q0 * wsh[24+i*3] + q1 * wsh[24+i*3+1] + q2 * wsh[24+i*3+2];
      mp = fmaxf(mp, pv); mt = fmaxf(mt, tv);
    }
  }
#pragma unroll
  for (int o = 32; o > 0; o >>= 1) { mp = fmaxf(mp, __shfl_down(mp, o)); mt = fmaxf(mt, __shfl_down(mt, o)); }
  __shared__ float rp[4], rt[4];
  int lane = tid & 63, wv = tid >> 6;
  if (!lane) { rp[wv] = mp; rt[wv] = mt; }
  __syncthreads();
  if (!tid) {
    mp = fmaxf(fmaxf(rp[0], rp[1]), fmaxf(rp[2], rp[3]));
    mt = fmaxf(fmaxf(rt[0], rt[1]), fmaxf(rt[2], rt[3]));
    atomicMax((int*)ws + OFF_MAX,     __float_as_int(mp));
    atomicMax((int*)ws + OFF_MAX + 1, __float_as_int(mt));
  }
}

// ---------------- Kernel D: per-block partial |P/mp - T/mt| sums ----------------
__global__ __launch_bounds__(256) void loss_kernel(float* __restrict__ ws) {
  __shared__ float wsh[48];
  int tid = threadIdx.x;
  if (tid < 48) wsh[tid] = (1.f / 3.f) / (ws[OFF_NORM + tid] + EPSF);
  __syncthreads();
  float imp = 1.f / (ws[OFF_MAX] + EPSF);
  float imt = 1.f / (ws[OFF_MAX + 1] + EPSF);
  float acc = 0.f;
  const float* S = ws + OFF_S;
  for (int idx = blockIdx.x * 256 + tid; idx < NPOS; idx += NB_LOSS * 256) {
    int b = idx / 9409, r = idx - b * 9409;
    size_t pb = (size_t)(b * 3) * 9409 + r;
    size_t tb = (size_t)(24 + b * 3) * 9409 + r;
    float p0 = S[pb], p1 = S[pb + 9409], p2 = S[pb + 2 * 9409];
    float q0 = S[tb], q1 = S[tb + 9409], q2 = S[tb + 2 * 9409];
#pragma unroll
    for (int i = 0; i < 8; i++) {
      float pv = (p0 * wsh[i*3] + p1 * wsh[i*3+1] + p2 * wsh[i*3+2]) * imp;
      float tv = (q0 * wsh[24+i*3] + q1 * wsh[24+i*3+1] + q2 * wsh[24+i*3+2]) * imt;
      acc += fabsf(pv - tv);
    }
  }
#pragma unroll
  for (int o = 32; o > 0; o >>= 1) acc += __shfl_down(acc, o);
  __shared__ float r[4];
  int lane = tid & 63, wv = tid >> 6;
  if (!lane) r[wv] = acc;
  __syncthreads();
  if (!tid) ws[OFF_PSUM + blockIdx.x] = (r[0] + r[1]) + (r[2] + r[3]);
}

// ---------------- Kernel E: final fixed-order reduce ----------------
__global__ __launch_bounds__(256) void final_kernel(const float* __restrict__ ws,
                                                    float* __restrict__ out) {
  int tid = threadIdx.x;
  float s = ws[OFF_PSUM + tid] + ws[OFF_PSUM + 256 + tid];
#pragma unroll
  for (int o = 32; o > 0; o >>= 1) s += __shfl_down(s, o);
  __shared__ float r[4];
  int lane = tid & 63, wv = tid >> 6;
  if (!lane) r[wv] = s;
  __syncthreads();
  if (!tid) out[0] = ((r[0] + r[1]) + (r[2] + r[3])) / 602176.0f;  // mean over 8*8*97*97
}

extern "C" void kernel_launch(void* const* d_in, const int* in_sizes, int n_in,
                              void* d_out, int out_size, void* d_ws, size_t ws_size,
                              hipStream_t stream) {
  const float* pred   = (const float*)d_in[0];
  const float* target = (const float*)d_in[1];
  float* ws  = (float*)d_ws;
  float* out = (float*)d_out;

  hipLaunchKernelGGL(stats_kernel,  dim3(48),      dim3(256), 0, stream, pred, target, ws);
  hipMemsetAsync((char*)d_ws + OFF_S * sizeof(float), 0, (size_t)48 * 9409 * sizeof(float), stream);
  hipLaunchKernelGGL(autocorr_mfma, dim3(48 * 16), dim3(256), 0, stream, pred, target, ws);
  hipLaunchKernelGGL(max_kernel,    dim3(256),     dim3(256), 0, stream, ws);
  hipLaunchKernelGGL(loss_kernel,   dim3(NB_LOSS), dim3(256), 0, stream, ws);
  hipLaunchKernelGGL(final_kernel,  dim3(1),       dim3(256), 0, stream, ws, out);
}

// Round 3
// 78.319 us; speedup vs baseline: 5.8487x; 1.2595x over previous
//
#include <hip/hip_runtime.h>
#include <math.h>

#define EPSF 1e-8f
#define HW 36864
#define NPOS (8*9409)
#define NB_LOSS 512

// ws float offsets
#define OFF_INV 0
#define OFF_NORM 48
#define OFF_MEAN 96
#define OFF_MAX 144
#define OFF_PSUM 160
#define OFF_S 1024          // 48 * 4753 floats: upper half S[sy 0..48][s 0..96]
#define SHALF 4753
#define OFF_PREP 229168     // ushort region: 48*36864 centered-bf16 images

// autocorr geometry
#define CY 12               // y0 rows per block; 16 chunks/img; 768 blocks
#define AROWS 75
#define APITCH 400          // bytes per A row (200 bf16 slots, 192 used)
#define CPB 720             // bytes per B parity copy (45 x 16B chunks)
#define RB 5760             // 8 parity copies per row
#define BB 11520            // 2 rows per buffer
#define ABYTES 30000
#define LDSB (ABYTES + 2*BB)   // 53040 -> 3 blocks/CU

typedef short short8 __attribute__((ext_vector_type(8)));
typedef float f32x4 __attribute__((ext_vector_type(4)));

__device__ __forceinline__ unsigned int pk2(float a, float b) {
  union { float f; unsigned int u; } x, y;
  x.f = a; y.f = b;
  unsigned int ra = x.u + 0x7fffu + ((x.u >> 16) & 1u);   // RNE to bf16
  unsigned int rb = y.u + 0x7fffu + ((y.u >> 16) & 1u);
  return (ra >> 16) | (rb & 0xffff0000u);
}

// ---------------- Kernel A: per-image mean / 1/(std+eps) / norm ----------------
__global__ __launch_bounds__(256) void stats_kernel(const float* __restrict__ pred,
                                                    const float* __restrict__ target,
                                                    float* __restrict__ ws) {
  int img = blockIdx.x;                 // img = t*24 + (b*3+c)
  int t = img / 24, local = img % 24;
  const float* src = (t ? target : pred) + (size_t)local * HW;
  int tid = threadIdx.x;
  float s = 0.f, sq = 0.f;
  const float4* src4 = (const float4*)src;
  for (int i = tid; i < HW/4; i += 256) {
    float4 v = src4[i];
    s  += (v.x + v.y) + (v.z + v.w);
    sq += (v.x*v.x + v.y*v.y) + (v.z*v.z + v.w*v.w);
  }
#pragma unroll
  for (int o = 32; o > 0; o >>= 1) { s += __shfl_down(s, o); sq += __shfl_down(sq, o); }
  __shared__ float rs[4], rq[4];
  int lane = tid & 63, wv = tid >> 6;
  if (lane == 0) { rs[wv] = s; rq[wv] = sq; }
  __syncthreads();
  if (tid == 0) {
    float S = (rs[0] + rs[1]) + (rs[2] + rs[3]);
    float Q = (rq[0] + rq[1]) + (rq[2] + rq[3]);
    float mean = S / (float)HW;
    float M2 = Q - S * S / (float)HW;
    M2 = fmaxf(M2, 0.f);
    float sd  = sqrtf(M2 / (float)(HW - 1));
    float inv = 1.f / (sd + EPSF);
    ws[OFF_MEAN + img] = mean;
    ws[OFF_INV  + img] = inv;
    ws[OFF_NORM + img] = sqrtf(M2) * inv;   // sqrt(sum xn^2)
    if (img == 0) { ws[OFF_MAX] = 0.f; ws[OFF_MAX + 1] = 0.f; }
  }
}

// ---------------- Kernel A2: centered bf16 image prep ----------------
__global__ __launch_bounds__(256) void prep_kernel(const float* __restrict__ pred,
                                                   const float* __restrict__ target,
                                                   float* __restrict__ ws) {
  int g = blockIdx.x * 256 + threadIdx.x;   // 864*256 = 221184 = 48*4608 exactly
  int img = g / 4608;
  int wi = g - img * 4608;
  int t = img / 24, local = img % 24;
  const float* src = (t ? target : pred) + (size_t)local * HW + wi * 8;
  float mean = ws[OFF_MEAN + img];
  float4 a = ((const float4*)src)[0], b = ((const float4*)src)[1];
  unsigned int d0 = pk2(a.x - mean, a.y - mean), d1 = pk2(a.z - mean, a.w - mean);
  unsigned int d2 = pk2(b.x - mean, b.y - mean), d3 = pk2(b.z - mean, b.w - mean);
  unsigned short* prep = (unsigned short*)(ws + OFF_PREP);
  int4 v; v.x = (int)d0; v.y = (int)d1; v.z = (int)d2; v.w = (int)d3;
  *(int4*)(prep + (size_t)img * HW + wi * 8) = v;
}

// ---------------- Kernel B: autocorrelation via bf16 MFMA ----------------
// Block = (img, 12-row y0-chunk). Wave w: khalf=w>>1 takes rows i=khalf,khalf+2,..;
// msel=w&1 picks sy range [32*msel, 32*msel+32) as 2 mt tiles of 16.
// B rows stored as 8 parity-shifted padded copies -> aligned ds_read_b128 windows.
__global__ __launch_bounds__(256, 3) void autocorr_mfma(float* __restrict__ ws) {
  int blk = blockIdx.x;
  int img = blk >> 4, chunk = blk & 15;
  int Y = chunk * CY;
  const unsigned short* prep = (const unsigned short*)(ws + OFF_PREP) + (size_t)img * HW;
  float inv = ws[OFF_INV + img];
  float scale = inv * inv;

  __shared__ __align__(16) char lds[LDSB];
  char* Al = lds;
  char* Bl = lds + ABYTES;

  int tid = threadIdx.x;
  int w = tid >> 6, lane = tid & 63, c = lane & 15, h = lane >> 4;
  int msel = w & 1, khalf = w >> 1;

  // ---- A stage: rows Y..Y+74 centered bf16 (zeros beyond image) ----
  int RV = 192 - Y;
  for (int m = tid; m < 1800; m += 256) {
    int r = m / 24, k = m - 24 * r;
    short8 v = (short8)(short)0;
    if (r < RV) v = *(const short8*)(prep + (Y + r) * 192 + k * 8);
    *(short8*)(Al + r * APITCH + k * 16) = v;
  }

  // ---- B stage: rows Y+2jd, Y+2jd+1 -> 8 parity copies each, buffer jd&1 ----
  auto stageB = [&](int jd) {
    int tsk = w + (lane << 2);          // bijective over 0..255; ~23 active/wave
    if (tsk < 90) {
      int row = (tsk >= 45) ? 1 : 0;
      int k = tsk - 45 * row;
      const unsigned short* srow = prep + (Y + 2 * jd + row) * 192;
      int e0 = 8 * k - 112;             // P[idx] = u[x = idx-112], zeros outside
      unsigned short q[15];
#pragma unroll
      for (int i2 = 0; i2 < 15; i2++) {
        int x = e0 + i2;
        q[i2] = ((unsigned)x < 192u) ? srow[x] : (unsigned short)0;
      }
      unsigned int D[8], Sh[7];
#pragma unroll
      for (int a2 = 0; a2 < 7; a2++) D[a2] = (unsigned)q[2*a2] | ((unsigned)q[2*a2+1] << 16);
      D[7] = (unsigned)q[14];
#pragma unroll
      for (int b2 = 0; b2 < 7; b2++) Sh[b2] = (D[b2] >> 16) | (D[b2+1] << 16);
      char* base = Bl + (jd & 1) * BB + row * RB + k * 16;
#pragma unroll
      for (int p = 0; p < 8; p++) {
        int4 v;
        if ((p & 1) == 0) { v.x = (int)D[p/2]; v.y = (int)D[p/2+1]; v.z = (int)D[p/2+2]; v.w = (int)D[p/2+3]; }
        else { v.x = (int)Sh[(p-1)/2]; v.y = (int)Sh[(p-1)/2+1]; v.z = (int)Sh[(p-1)/2+2]; v.w = (int)Sh[(p-1)/2+3]; }
        *(int4*)(base + p * CPB) = v;
      }
    }
  };

  // lane-constant B addressing: copy p = (-c) mod 8, base chunk 20+h-q, window v=4t-2nt
  int p_l = (8 - (c & 7)) & 7;
  int q_l = (c == 0) ? 0 : ((c <= 8) ? 1 : 2);
  int LB0 = p_l * CPB + 16 * (20 + h - q_l) - 192;   // window wi at LB0 + 32*wi

  f32x4 acc[2][7];
#pragma unroll
  for (int mt = 0; mt < 2; mt++)
#pragma unroll
    for (int nt = 0; nt < 7; nt++) acc[mt][nt] = (f32x4)0.f;

  stageB(0);
  __syncthreads();

  for (int j = 0; j < 6; j++) {
    if (j < 5) stageB(j + 1);
    int i = 2 * j + khalf;
    const char* pA0 = Al + (i + 32 * msel + c) * APITCH + 16 * h;
    const char* pB  = Bl + (j & 1) * BB + khalf * RB + LB0;
    short8 Wf[17];
#pragma unroll
    for (int wi2 = 0; wi2 < 7; wi2++) Wf[wi2] = *(const short8*)(pB + 32 * wi2);
#pragma unroll
    for (int t = 0; t < 6; t++) {
      if (t) {
        Wf[2*t+5] = *(const short8*)(pB + 32 * (2*t+5));
        Wf[2*t+6] = *(const short8*)(pB + 32 * (2*t+6));
      }
#pragma unroll
      for (int mt = 0; mt < 2; mt++) {
        short8 Af = *(const short8*)(pA0 + mt * (16 * APITCH) + 64 * t);
#pragma unroll
        for (int nt = 0; nt < 7; nt++)
          acc[mt][nt] = __builtin_amdgcn_mfma_f32_16x16x32_bf16(Af, Wf[2*t+6-nt], acc[mt][nt], 0, 0, 0);
      }
    }
    __syncthreads();
  }

  // ---- combine khalf pairs through LDS (alias A region), then atomics ----
  if (khalf == 1) {
#pragma unroll
    for (int mt = 0; mt < 2; mt++)
#pragma unroll
      for (int nt = 0; nt < 7; nt++)
        *(f32x4*)(lds + ((((msel << 6) + lane) * 14) + mt * 7 + nt) * 16) = acc[mt][nt];
  }
  __syncthreads();
  if (khalf == 0) {
    float* S2 = ws + OFF_S + (size_t)img * SHALF;
#pragma unroll
    for (int mt = 0; mt < 2; mt++) {
#pragma unroll
      for (int nt = 0; nt < 7; nt++) {
        f32x4 o = *(f32x4*)(lds + ((((msel << 6) + lane) * 14) + mt * 7 + nt) * 16);
        int s = 16 * nt + c;
#pragma unroll
        for (int r = 0; r < 4; r++) {
          int sy = 32 * msel + 16 * mt + 4 * h + r;
          if (sy <= 48 && s <= 96) {
            float v2 = (acc[mt][nt][r] + o[r]) * scale;
            atomicAdd(&S2[sy * 97 + s], v2);
          }
        }
      }
    }
  }
}

// mirror fetch: full (row,col) in [0,97)^2 from upper-half storage
__device__ __forceinline__ int half_off(int row, int col) {
  return (row >= 48) ? ((row - 48) * 97 + col) : ((48 - row) * 97 + (96 - col));
}

// ---------------- Kernel C: global max of P (pred) and T (target) ----------------
__global__ __launch_bounds__(256) void max_kernel(float* __restrict__ ws) {
  __shared__ float wsh[48];      // (1/3)/(norm+eps), [t*24 + i*3 + c]
  int tid = threadIdx.x;
  if (tid < 48) wsh[tid] = (1.f / 3.f) / (ws[OFF_NORM + tid] + EPSF);
  __syncthreads();
  float mp = 0.f, mt2 = 0.f;
  const float* S = ws + OFF_S;
  for (int idx = blockIdx.x * 256 + tid; idx < NPOS; idx += gridDim.x * 256) {
    int b = idx / 9409, r = idx - b * 9409;
    int row = r / 97, col = r - 97 * row;
    int off = half_off(row, col);
    size_t pb = (size_t)(b * 3) * SHALF + off;
    size_t tb = (size_t)(24 + b * 3) * SHALF + off;
    float p0 = S[pb], p1 = S[pb + SHALF], p2 = S[pb + 2 * SHALF];
    float q0 = S[tb], q1 = S[tb + SHALF], q2 = S[tb + 2 * SHALF];
#pragma unroll
    for (int i = 0; i < 8; i++) {
      float pv = p0 * wsh[i*3] + p1 * wsh[i*3+1] + p2 * wsh[i*3+2];
      float tv = q0 * wsh[24+i*3] + q1 * wsh[24+i*3+1] + q2 * wsh[24+i*3+2];
      mp = fmaxf(mp, pv); mt2 = fmaxf(mt2, tv);
    }
  }
#pragma unroll
  for (int o = 32; o > 0; o >>= 1) { mp = fmaxf(mp, __shfl_down(mp, o)); mt2 = fmaxf(mt2, __shfl_down(mt2, o)); }
  __shared__ float rp[4], rt[4];
  int lane = tid & 63, wv = tid >> 6;
  if (!lane) { rp[wv] = mp; rt[wv] = mt2; }
  __syncthreads();
  if (!tid) {
    mp = fmaxf(fmaxf(rp[0], rp[1]), fmaxf(rp[2], rp[3]));
    mt2 = fmaxf(fmaxf(rt[0], rt[1]), fmaxf(rt[2], rt[3]));
    atomicMax((int*)ws + OFF_MAX,     __float_as_int(mp));   // positive floats
    atomicMax((int*)ws + OFF_MAX + 1, __float_as_int(mt2));
  }
}

// ---------------- Kernel D: per-block partial |P/mp - T/mt| sums ----------------
__global__ __launch_bounds__(256) void loss_kernel(float* __restrict__ ws) {
  __shared__ float wsh[48];
  int tid = threadIdx.x;
  if (tid < 48) wsh[tid] = (1.f / 3.f) / (ws[OFF_NORM + tid] + EPSF);
  __syncthreads();
  float imp = 1.f / (ws[OFF_MAX] + EPSF);
  float imt = 1.f / (ws[OFF_MAX + 1] + EPSF);
  float acc = 0.f;
  const float* S = ws + OFF_S;
  for (int idx = blockIdx.x * 256 + tid; idx < NPOS; idx += NB_LOSS * 256) {
    int b = idx / 9409, r = idx - b * 9409;
    int row = r / 97, col = r - 97 * row;
    int off = half_off(row, col);
    size_t pb = (size_t)(b * 3) * SHALF + off;
    size_t tb = (size_t)(24 + b * 3) * SHALF + off;
    float p0 = S[pb], p1 = S[pb + SHALF], p2 = S[pb + 2 * SHALF];
    float q0 = S[tb], q1 = S[tb + SHALF], q2 = S[tb + 2 * SHALF];
#pragma unroll
    for (int i = 0; i < 8; i++) {
      float pv = (p0 * wsh[i*3] + p1 * wsh[i*3+1] + p2 * wsh[i*3+2]) * imp;
      float tv = (q0 * wsh[24+i*3] + q1 * wsh[24+i*3+1] + q2 * wsh[24+i*3+2]) * imt;
      acc += fabsf(pv - tv);
    }
  }
#pragma unroll
  for (int o = 32; o > 0; o >>= 1) acc += __shfl_down(acc, o);
  __shared__ float r[4];
  int lane = tid & 63, wv = tid >> 6;
  if (!lane) r[wv] = acc;
  __syncthreads();
  if (!tid) ws[OFF_PSUM + blockIdx.x] = (r[0] + r[1]) + (r[2] + r[3]);
}

// ---------------- Kernel E: final fixed-order reduce ----------------
__global__ __launch_bounds__(256) void final_kernel(const float* __restrict__ ws,
                                                    float* __restrict__ out) {
  int tid = threadIdx.x;
  float s = ws[OFF_PSUM + tid] + ws[OFF_PSUM + 256 + tid];
#pragma unroll
  for (int o = 32; o > 0; o >>= 1) s += __shfl_down(s, o);
  __shared__ float r[4];
  int lane = tid & 63, wv = tid >> 6;
  if (!lane) r[wv] = s;
  __syncthreads();
  if (!tid) out[0] = ((r[0] + r[1]) + (r[2] + r[3])) / 602176.0f;  // 8*8*97*97
}

extern "C" void kernel_launch(void* const* d_in, const int* in_sizes, int n_in,
                              void* d_out, int out_size, void* d_ws, size_t ws_size,
                              hipStream_t stream) {
  const float* pred   = (const float*)d_in[0];
  const float* target = (const float*)d_in[1];
  float* ws  = (float*)d_ws;
  float* out = (float*)d_out;

  hipLaunchKernelGGL(stats_kernel,  dim3(48),      dim3(256), 0, stream, pred, target, ws);
  hipLaunchKernelGGL(prep_kernel,   dim3(864),     dim3(256), 0, stream, pred, target, ws);
  hipMemsetAsync((char*)d_ws + OFF_S * sizeof(float), 0, (size_t)48 * SHALF * sizeof(float), stream);
  hipLaunchKernelGGL(autocorr_mfma, dim3(48 * 16), dim3(256), 0, stream, ws);
  hipLaunchKernelGGL(max_kernel,    dim3(256),     dim3(256), 0, stream, ws);
  hipLaunchKernelGGL(loss_kernel,   dim3(NB_LOSS), dim3(256), 0, stream, ws);
  hipLaunchKernelGGL(final_kernel,  dim3(1),       dim3(256), 0, stream, ws, out);
}

// Round 4
// 71.645 us; speedup vs baseline: 6.3936x; 1.0932x over previous
//
#include <hip/hip_runtime.h>
#include <math.h>

#define EPSF 1e-8f
#define HW 36864
#define SHALF 4753          // 49*97 stored upper half of each corr map
#define NIDX (8*SHALF)      // per-j iteration domain for max/loss

// ws float offsets
#define OFF_INV   0
#define OFF_NORM  48
#define OFF_MAX   144       // [0]=pred max bits, [1]=target max bits (int-ordered)
#define OFF_ACC   146       // loss accumulator
#define OFF_CNT   147       // loss block counter (int)
#define OFF_PART  160       // 48*2 floats: per-image sum/sumsq atomic partials
#define OFF_CTR   256       // 48 ints: per-image arrival counters
#define OFF_S     1024      // 48*SHALF floats
#define OFF_PREP  229168    // ushort region: 48*36864 centered-bf16 images

// autocorr geometry
#define CY 12               // y0 rows per block; 16 chunks/img; 768 blocks = 3/CU exactly
#define AROWS 75
#define APITCH 400          // bytes per A row
#define CPB 720             // bytes per B parity copy (45 chunks x 16B)
#define RB 5824             // bytes per staged B row (8 padded copies)
#define ABYTES 30000
#define BBYTES (4*RB)       // 4 rows, single buffer
#define LDSB (ABYTES + BBYTES)   // 53296 -> 3 blocks/CU

#define MAXB 64
#define LOSSB 64

typedef short short8 __attribute__((ext_vector_type(8)));
typedef float f32x4 __attribute__((ext_vector_type(4)));

__device__ __forceinline__ unsigned int pk2(float a, float b) {
  union { float f; unsigned int u; } x, y;
  x.f = a; y.f = b;
  unsigned int ra = x.u + 0x7fffu + ((x.u >> 16) & 1u);   // RNE to bf16
  unsigned int rb = y.u + 0x7fffu + ((y.u >> 16) & 1u);
  return (ra >> 16) | (rb & 0xffff0000u);
}

// ---------------- Kernel 1: fused stats + centered-bf16 prep + S zero ----------------
// 192 blocks = 4 per image; cross-block mean via atomic partials + counter spin.
__global__ __launch_bounds__(256) void stats_prep(const float* __restrict__ pred,
                                                  const float* __restrict__ target,
                                                  float* __restrict__ ws) {
  int blk = blockIdx.x, tid = threadIdx.x;
  int img = blk >> 2, qtr = blk & 3;
  int t = img / 24, local = img % 24;
  const float* src = (t ? target : pred) + (size_t)local * HW + qtr * 9216;

  // zero the S accumulation region (before autocorr dispatch)
  float* S = ws + OFF_S;
  for (int i = blk * 256 + tid; i < 48 * SHALF; i += 192 * 256) S[i] = 0.f;

  // pass 1: quarter reduce
  const float4* s4 = (const float4*)src;
  float s = 0.f, sq = 0.f;
  for (int i = tid; i < 2304; i += 256) {
    float4 v = s4[i];
    s  += (v.x + v.y) + (v.z + v.w);
    sq += (v.x*v.x + v.y*v.y) + (v.z*v.z + v.w*v.w);
  }
#pragma unroll
  for (int o = 32; o > 0; o >>= 1) { s += __shfl_down(s, o); sq += __shfl_down(sq, o); }
  __shared__ float rs[4], rq[4], bcast[1];
  int lane = tid & 63, wv = tid >> 6;
  if (!lane) { rs[wv] = s; rq[wv] = sq; }
  __syncthreads();
  if (!tid) {
    s  = (rs[0] + rs[1]) + (rs[2] + rs[3]);
    sq = (rq[0] + rq[1]) + (rq[2] + rq[3]);
    atomicAdd(&ws[OFF_PART + 2*img],     s);
    atomicAdd(&ws[OFF_PART + 2*img + 1], sq);
    __threadfence();
    atomicAdd((int*)ws + OFF_CTR + img, 1);
    while (atomicAdd((int*)ws + OFF_CTR + img, 0) < 4) { }
    float S1 = atomicAdd(&ws[OFF_PART + 2*img],     0.f);
    float Q  = atomicAdd(&ws[OFF_PART + 2*img + 1], 0.f);
    float mean = S1 / (float)HW;
    float M2 = fmaxf(Q - S1 * S1 / (float)HW, 0.f);
    float inv = 1.f / (sqrtf(M2 / (float)(HW - 1)) + EPSF);
    bcast[0] = mean;
    if (qtr == 0) {
      ws[OFF_INV  + img] = inv;
      ws[OFF_NORM + img] = sqrtf(M2) * inv;   // sqrt(sum xn^2)
    }
  }
  __syncthreads();
  float mean = bcast[0];

  // pass 2: centered bf16 prep of this quarter
  unsigned short* prep = (unsigned short*)(ws + OFF_PREP) + (size_t)img * HW + qtr * 9216;
  for (int i = tid; i < 2304; i += 256) {
    float4 v = s4[i];
    uint2 d; d.x = pk2(v.x - mean, v.y - mean); d.y = pk2(v.z - mean, v.w - mean);
    *(uint2*)(prep + i * 4) = d;
  }
}

// ---------------- Kernel 2: autocorrelation via bf16 MFMA ----------------
// Block = (img, 12-row y0-chunk). Wave w = K-split (rows 4j+w); each wave computes the
// FULL mt=4 x nt=7 tile set (sy 0..63, s 0..111). B rows staged as 8 parity-shifted
// copies with bank-equalizing pads {16,80,32,80,...} -> all ds_read_b128 are 2-way max.
__global__ __launch_bounds__(256, 3) void autocorr_mfma(float* __restrict__ ws) {
  int blk = blockIdx.x;
  int img = blk >> 4, chunk = blk & 15;
  int Y = chunk * CY;
  const unsigned short* prep = (const unsigned short*)(ws + OFF_PREP) + (size_t)img * HW;
  float inv = ws[OFF_INV + img];
  float scale = inv * inv;

  __shared__ __align__(16) char lds[LDSB];
  char* Al = lds;
  char* Bl = lds + ABYTES;

  int tid = threadIdx.x;
  int w = tid >> 6, lane = tid & 63, c = lane & 15, h = lane >> 4;

  // ---- A stage: rows Y..Y+74 (zeros beyond image) ----
  int RV = 192 - Y;
  for (int m = tid; m < 1800; m += 256) {
    int r = m / 24, k = m - r * 24;
    short8 v = (short8)(short)0;
    if (r < RV) v = *(const short8*)(prep + (Y + r) * 192 + k * 8);
    *(short8*)(Al + r * APITCH + k * 16) = v;
  }

  // lane-constant B addressing: copy p = (-c) mod 8, pad-equalized
  int p_l = (8 - (c & 7)) & 7;
  int q_l = (c == 0) ? 0 : ((c <= 8) ? 1 : 2);
  int pad_l = (p_l == 0) ? 16 : ((p_l & 1) ? 80 : 32);
  int LB0 = p_l * CPB + pad_l + 16 * (h - q_l) + 128;   // window wi at LB0 + 32*wi

  f32x4 acc[4][7];
#pragma unroll
  for (int mt = 0; mt < 4; mt++)
#pragma unroll
    for (int nt = 0; nt < 7; nt++) acc[mt][nt] = (f32x4)0.f;

  for (int j = 0; j < 3; ++j) {
    __syncthreads();                       // previous compute done before overwrite
    if (tid < 180) {                       // stage rows Y+4j .. Y+4j+3
      int rr = tid / 45, k = tid - rr * 45;
      const unsigned short* srow = prep + (Y + 4 * j + rr) * 192;
      int e0 = 8 * k - 112;                // P[E] = u[x = E-112]
      unsigned short q[15];
#pragma unroll
      for (int i2 = 0; i2 < 15; i2++) {
        int x = e0 + i2;
        q[i2] = ((unsigned)x < 192u) ? srow[x] : (unsigned short)0;
      }
      unsigned int D[8], Sh[7];
#pragma unroll
      for (int a2 = 0; a2 < 7; a2++) D[a2] = (unsigned)q[2*a2] | ((unsigned)q[2*a2+1] << 16);
      D[7] = (unsigned)q[14];
#pragma unroll
      for (int b2 = 0; b2 < 7; b2++) Sh[b2] = (D[b2] >> 16) | (D[b2+1] << 16);
      char* base = Bl + rr * RB + k * 16;
#pragma unroll
      for (int p = 0; p < 8; p++) {
        int pb = (p == 0) ? 16 : ((p & 1) ? 80 : 32);
        int4 v;
        if ((p & 1) == 0) { v.x = (int)D[p/2]; v.y = (int)D[p/2+1]; v.z = (int)D[p/2+2]; v.w = (int)D[p/2+3]; }
        else { v.x = (int)Sh[(p-1)/2]; v.y = (int)Sh[(p-1)/2+1]; v.z = (int)Sh[(p-1)/2+2]; v.w = (int)Sh[(p-1)/2+3]; }
        *(int4*)(base + p * CPB + pb) = v;
      }
    }
    __syncthreads();

    const char* pB = Bl + w * RB + LB0;
    const char* pA = Al + ((4 * j + w) + c) * APITCH + 16 * h;
    short8 Wf[17];
#pragma unroll
    for (int wi = 0; wi < 7; wi++) Wf[wi] = *(const short8*)(pB + 32 * wi);
#pragma unroll
    for (int t = 0; t < 6; t++) {
      if (t) {
        Wf[2*t+5] = *(const short8*)(pB + 32 * (2*t+5));
        Wf[2*t+6] = *(const short8*)(pB + 32 * (2*t+6));
      }
#pragma unroll
      for (int mt = 0; mt < 4; mt++) {
        short8 Af = *(const short8*)(pA + mt * (16 * APITCH) + 64 * t);
#pragma unroll
        for (int nt = 0; nt < 7; nt++)
          acc[mt][nt] = __builtin_amdgcn_mfma_f32_16x16x32_bf16(Af, Wf[2*t+6-nt], acc[mt][nt], 0, 0, 0);
      }
    }
  }

  // ---- epilogue: K-combine across waves via LDS (stride 240 -> 2-way banks) ----
  // sub-round 1: waves 2,3 dump acc[0..1]; waves 0,1 add
  __syncthreads();
  if (w >= 2) {
    char* rg = lds + (w - 2) * 15360 + lane * 240;
#pragma unroll
    for (int mt = 0; mt < 2; mt++)
#pragma unroll
      for (int nt = 0; nt < 7; nt++) *(f32x4*)(rg + (mt*7+nt)*16) = acc[mt][nt];
  }
  __syncthreads();
  if (w < 2) {
    const char* rg = lds + w * 15360 + lane * 240;
#pragma unroll
    for (int mt = 0; mt < 2; mt++)
#pragma unroll
      for (int nt = 0; nt < 7; nt++) {
        f32x4 o = *(const f32x4*)(rg + (mt*7+nt)*16);
        acc[mt][nt][0] += o[0]; acc[mt][nt][1] += o[1]; acc[mt][nt][2] += o[2]; acc[mt][nt][3] += o[3];
      }
  }
  // sub-round 2: same for acc[2..3]
  __syncthreads();
  if (w >= 2) {
    char* rg = lds + (w - 2) * 15360 + lane * 240;
#pragma unroll
    for (int mt = 2; mt < 4; mt++)
#pragma unroll
      for (int nt = 0; nt < 7; nt++) *(f32x4*)(rg + ((mt-2)*7+nt)*16) = acc[mt][nt];
  }
  __syncthreads();
  if (w < 2) {
    const char* rg = lds + w * 15360 + lane * 240;
#pragma unroll
    for (int mt = 2; mt < 4; mt++)
#pragma unroll
      for (int nt = 0; nt < 7; nt++) {
        f32x4 o = *(const f32x4*)(rg + ((mt-2)*7+nt)*16);
        acc[mt][nt][0] += o[0]; acc[mt][nt][1] += o[1]; acc[mt][nt][2] += o[2]; acc[mt][nt][3] += o[3];
      }
  }
  // cross-swap: w1 -> mt{0,1} to w0's side; w0 -> mt{2,3} to w1's side
  __syncthreads();
  if (w == 1) {
    char* rg = lds + lane * 240;
#pragma unroll
    for (int mt = 0; mt < 2; mt++)
#pragma unroll
      for (int nt = 0; nt < 7; nt++) *(f32x4*)(rg + (mt*7+nt)*16) = acc[mt][nt];
  }
  if (w == 0) {
    char* rg = lds + 15360 + lane * 240;
#pragma unroll
    for (int mt = 2; mt < 4; mt++)
#pragma unroll
      for (int nt = 0; nt < 7; nt++) *(f32x4*)(rg + ((mt-2)*7+nt)*16) = acc[mt][nt];
  }
  __syncthreads();
  float* S2 = ws + OFF_S + (size_t)img * SHALF;
  if (w == 0) {
    const char* rg = lds + lane * 240;
#pragma unroll
    for (int mt = 0; mt < 2; mt++)
#pragma unroll
      for (int nt = 0; nt < 7; nt++) {
        f32x4 o = *(const f32x4*)(rg + (mt*7+nt)*16);
        int s = 16 * nt + c;
#pragma unroll
        for (int r = 0; r < 4; r++) {
          int sy = 16 * mt + 4 * h + r;
          if (sy <= 48 && s <= 96)
            atomicAdd(&S2[sy * 97 + s], (acc[mt][nt][r] + o[r]) * scale);
        }
      }
  } else if (w == 1) {
    const char* rg = lds + 15360 + lane * 240;
#pragma unroll
    for (int mt = 2; mt < 4; mt++)
#pragma unroll
      for (int nt = 0; nt < 7; nt++) {
        f32x4 o = *(const f32x4*)(rg + ((mt-2)*7+nt)*16);
        int s = 16 * nt + c;
#pragma unroll
        for (int r = 0; r < 4; r++) {
          int sy = 16 * mt + 4 * h + r;
          if (sy <= 48 && s <= 96)
            atomicAdd(&S2[sy * 97 + s], (acc[mt][nt][r] + o[r]) * scale);
        }
      }
  }
}

// ---------------- Kernel 3: global max over stored half-domain ----------------
__global__ __launch_bounds__(256) void max_kernel(float* __restrict__ ws) {
  __shared__ float wsh[48];
  int tid = threadIdx.x;
  if (tid < 48) wsh[tid] = (1.f / 3.f) / (ws[OFF_NORM + tid] + EPSF);
  __syncthreads();
  float mp = 0.f, mt2 = 0.f;
  const float* S = ws + OFF_S;
  for (int idx = blockIdx.x * 256 + tid; idx < NIDX; idx += MAXB * 256) {
    int j = idx / SHALF, off = idx - j * SHALF;
    const float* Pp = S + (size_t)(3 * j) * SHALF + off;
    const float* Tt = S + (size_t)(24 + 3 * j) * SHALF + off;
    float p0 = Pp[0], p1 = Pp[SHALF], p2 = Pp[2 * SHALF];
    float q0 = Tt[0], q1 = Tt[SHALF], q2 = Tt[2 * SHALF];
#pragma unroll
    for (int i = 0; i < 8; i++) {
      float pv = p0 * wsh[i*3] + p1 * wsh[i*3+1] + p2 * wsh[i*3+2];
      float tv = q0 * wsh[24+i*3] + q1 * wsh[24+i*3+1] + q2 * wsh[24+i*3+2];
      mp = fmaxf(mp, pv); mt2 = fmaxf(mt2, tv);
    }
  }
#pragma unroll
  for (int o = 32; o > 0; o >>= 1) { mp = fmaxf(mp, __shfl_down(mp, o)); mt2 = fmaxf(mt2, __shfl_down(mt2, o)); }
  __shared__ float rp[4], rt[4];
  int lane = tid & 63, wv = tid >> 6;
  if (!lane) { rp[wv] = mp; rt[wv] = mt2; }
  __syncthreads();
  if (!tid) {
    mp  = fmaxf(fmaxf(rp[0], rp[1]), fmaxf(rp[2], rp[3]));
    mt2 = fmaxf(fmaxf(rt[0], rt[1]), fmaxf(rt[2], rt[3]));
    atomicMax((int*)ws + OFF_MAX,     __float_as_int(mp));    // positive floats: int order
    atomicMax((int*)ws + OFF_MAX + 1, __float_as_int(mt2));
  }
}

// ---------------- Kernel 4: loss partials + last-block finalize ----------------
__global__ __launch_bounds__(256) void loss_final(float* __restrict__ ws,
                                                  float* __restrict__ out) {
  __shared__ float wsh[48];
  int tid = threadIdx.x;
  if (tid < 48) wsh[tid] = (1.f / 3.f) / (ws[OFF_NORM + tid] + EPSF);
  __syncthreads();
  float imp = 1.f / (__int_as_float(((const int*)ws)[OFF_MAX])     + EPSF);
  float imt = 1.f / (__int_as_float(((const int*)ws)[OFF_MAX + 1]) + EPSF);
  float acc = 0.f;
  const float* S = ws + OFF_S;
  for (int idx = blockIdx.x * 256 + tid; idx < NIDX; idx += LOSSB * 256) {
    int j = idx / SHALF, off = idx - j * SHALF;
    float wgt = (off < 97) ? 1.f : 2.f;    // sy=0 row counted once, others mirror x2
    const float* Pp = S + (size_t)(3 * j) * SHALF + off;
    const float* Tt = S + (size_t)(24 + 3 * j) * SHALF + off;
    float p0 = Pp[0], p1 = Pp[SHALF], p2 = Pp[2 * SHALF];
    float q0 = Tt[0], q1 = Tt[SHALF], q2 = Tt[2 * SHALF];
    float a8 = 0.f;
#pragma unroll
    for (int i = 0; i < 8; i++) {
      float pv = (p0 * wsh[i*3] + p1 * wsh[i*3+1] + p2 * wsh[i*3+2]) * imp;
      float tv = (q0 * wsh[24+i*3] + q1 * wsh[24+i*3+1] + q2 * wsh[24+i*3+2]) * imt;
      a8 += fabsf(pv - tv);
    }
    acc += wgt * a8;
  }
#pragma unroll
  for (int o = 32; o > 0; o >>= 1) acc += __shfl_down(acc, o);
  __shared__ float r[4];
  int lane = tid & 63, wv = tid >> 6;
  if (!lane) r[wv] = acc;
  __syncthreads();
  if (!tid) {
    float bs = (r[0] + r[1]) + (r[2] + r[3]);
    atomicAdd(&ws[OFF_ACC], bs);
    __threadfence();
    int old = atomicAdd((int*)ws + OFF_CNT, 1);
    if (old == LOSSB - 1) {
      float total = atomicAdd(&ws[OFF_ACC], 0.f);
      out[0] = total * (1.0f / 602176.0f);   // mean over 8*8*97*97
    }
  }
}

extern "C" void kernel_launch(void* const* d_in, const int* in_sizes, int n_in,
                              void* d_out, int out_size, void* d_ws, size_t ws_size,
                              hipStream_t stream) {
  const float* pred   = (const float*)d_in[0];
  const float* target = (const float*)d_in[1];
  float* ws  = (float*)d_ws;
  float* out = (float*)d_out;

  // zero counters/partials/max/acc region: floats [144, 304)
  hipMemsetAsync((char*)d_ws + 144 * sizeof(float), 0, (304 - 144) * sizeof(float), stream);
  hipLaunchKernelGGL(stats_prep,    dim3(192),     dim3(256), 0, stream, pred, target, ws);
  hipLaunchKernelGGL(autocorr_mfma, dim3(48 * 16), dim3(256), 0, stream, ws);
  hipLaunchKernelGGL(max_kernel,    dim3(MAXB),    dim3(256), 0, stream, ws);
  hipLaunchKernelGGL(loss_final,    dim3(LOSSB),   dim3(256), 0, stream, ws, out);
}